// Round 1
// baseline (926.488 us; speedup 1.0000x reference)
//
#include <hip/hip_runtime.h>

#define N_NODES 50000
#define N_EDGES 800000
#define D 64
#define H 128

// ---------------------------------------------------------------------------
// Kernel 1: scatter-add  agg[row[e]] += x[col[e]]   (16 lanes per edge, float4)
// ---------------------------------------------------------------------------
__global__ __launch_bounds__(256) void gin_scatter(
    const float* __restrict__ x,
    const int*   __restrict__ row,
    const int*   __restrict__ col,
    float*       __restrict__ agg)
{
    long long tid = (long long)blockIdx.x * blockDim.x + threadIdx.x;
    int e = (int)(tid >> 4);          // 16 lanes per edge
    int q = ((int)tid & 15) * 4;      // feature quad offset
    if (e >= N_EDGES) return;

    int r = row[e];
    int c = col[e];

    const float4 v = *(const float4*)(x + (long long)c * D + q);
    float* dst = agg + (long long)r * D + q;
    atomicAdd(dst + 0, v.x);
    atomicAdd(dst + 1, v.y);
    atomicAdd(dst + 2, v.z);
    atomicAdd(dst + 3, v.w);
}

// ---------------------------------------------------------------------------
// Kernel 2: fused  out = relu(((1+eps)*x + agg) @ W1 + b1) @ W2 + b2
// One wave (64 lanes) per node. W1/W2 staged in LDS (64 KB -> 2 blocks/CU).
// Lane j holds h[j]; hidden[j], hidden[j+64] accumulated via shfl-broadcast.
// LDS reads are stride-1 across lanes => only 2-way bank aliasing (free).
// ---------------------------------------------------------------------------
__global__ __launch_bounds__(256) void gin_mlp(
    const float* __restrict__ x,
    const float* __restrict__ agg,
    const float* __restrict__ W1,
    const float* __restrict__ b1,
    const float* __restrict__ W2,
    const float* __restrict__ b2,
    const float* __restrict__ eps,
    float*       __restrict__ out)
{
    __shared__ float W1s[D * H];   // 32 KB
    __shared__ float W2s[H * D];   // 32 KB

    int t = threadIdx.x;
    for (int i = t; i < D * H; i += 256) W1s[i] = W1[i];
    for (int i = t; i < H * D; i += 256) W2s[i] = W2[i];
    __syncthreads();

    int wave = t >> 6;
    int lane = t & 63;
    int node = blockIdx.x * 4 + wave;
    if (node >= N_NODES) return;

    float epsv = 1.0f + eps[0];
    long long base = (long long)node * D;

    // h[lane] for this node
    float hv = fmaf(epsv, x[base + lane], agg[base + lane]);

    // Layer 1: hidden = relu(h @ W1 + b1); lane j computes hidden[j], hidden[j+64]
    float acc1 = b1[lane];
    float acc2 = b1[lane + 64];
    #pragma unroll
    for (int k = 0; k < D; ++k) {
        float hk = __shfl(hv, k);
        acc1 = fmaf(hk, W1s[k * H + lane],      acc1);
        acc2 = fmaf(hk, W1s[k * H + lane + 64], acc2);
    }
    acc1 = fmaxf(acc1, 0.0f);
    acc2 = fmaxf(acc2, 0.0f);

    // Layer 2: out = hidden @ W2 + b2; lane j computes out[j]
    float o = b2[lane];
    #pragma unroll
    for (int k = 0; k < D; ++k) {
        o = fmaf(__shfl(acc1, k), W2s[k * D + lane],        o);
        o = fmaf(__shfl(acc2, k), W2s[(k + 64) * D + lane], o);
    }

    out[base + lane] = o;
}

// ---------------------------------------------------------------------------
extern "C" void kernel_launch(void* const* d_in, const int* in_sizes, int n_in,
                              void* d_out, int out_size, void* d_ws, size_t ws_size,
                              hipStream_t stream) {
    const float* x   = (const float*)d_in[0];
    const int*   ei  = (const int*)  d_in[1];   // [2, 800000], row-major
    const float* W1  = (const float*)d_in[2];
    const float* b1  = (const float*)d_in[3];
    const float* W2  = (const float*)d_in[4];
    const float* b2  = (const float*)d_in[5];
    const float* eps = (const float*)d_in[6];
    float* out = (float*)d_out;

    float* agg = (float*)d_ws;   // N_NODES * D floats = 12.8 MB

    // d_ws is re-poisoned to 0xAA before every launch — must zero it ourselves.
    hipMemsetAsync(agg, 0, (size_t)N_NODES * D * sizeof(float), stream);

    const int* row = ei;
    const int* col = ei + N_EDGES;

    // 16 lanes per edge -> 12.8M threads -> 50000 blocks of 256
    int scatter_blocks = (N_EDGES * 16) / 256;
    gin_scatter<<<scatter_blocks, 256, 0, stream>>>(x, row, col, agg);

    // one wave per node, 4 waves per block
    int mlp_blocks = (N_NODES + 3) / 4;
    gin_mlp<<<mlp_blocks, 256, 0, stream>>>(x, agg, W1, b1, W2, b2, eps, out);
}

// Round 2
// 377.198 us; speedup vs baseline: 2.4562x; 2.4562x over previous
//
#include <hip/hip_runtime.h>

#define N_NODES 50000
#define N_EDGES 800000
#define D 64
#define H 128

// ---------------------------------------------------------------------------
// Workspace layout (ints):
//   counts  [N_NODES]
//   offsets [N_NODES+1]
//   cursor  [N_NODES]
//   csr_col [N_EDGES]
// Total ~3.8 MB (well under the 12.8 MB we used in round 1).
// ---------------------------------------------------------------------------

// Phase A: histogram of destination nodes. 800k int atomics (64x fewer than
// the 51.2M float atomics of round 1, which each wrote through to HBM).
__global__ __launch_bounds__(256) void hist_kernel(
    const int* __restrict__ row, int* __restrict__ counts)
{
    int e = blockIdx.x * 256 + threadIdx.x;
    if (e < N_EDGES) atomicAdd(&counts[row[e]], 1);
}

// Phase B: exclusive prefix sum of counts -> offsets[0..N], also seeds cursor.
// Single block, 1024 threads (16 waves), shfl-based scans, ~49 chunks.
__global__ __launch_bounds__(1024) void scan_kernel(
    const int* __restrict__ counts,
    int* __restrict__ offsets,
    int* __restrict__ cursor)
{
    __shared__ int wsum[16];
    __shared__ int wofs[16];
    __shared__ int btot;
    int t = threadIdx.x, lane = t & 63, wid = t >> 6;
    int carry = 0;
    for (int base = 0; base < N_NODES; base += 1024) {
        int i = base + t;
        int v = (i < N_NODES) ? counts[i] : 0;
        int incl = v;
        #pragma unroll
        for (int d = 1; d < 64; d <<= 1) {
            int y = __shfl_up(incl, d);
            if (lane >= d) incl += y;
        }
        if (lane == 63) wsum[wid] = incl;
        __syncthreads();
        if (wid == 0) {
            int wv = (lane < 16) ? wsum[lane] : 0;
            int winc = wv;
            #pragma unroll
            for (int d = 1; d < 16; d <<= 1) {
                int y = __shfl_up(winc, d);
                if (lane >= d) winc += y;
            }
            if (lane < 16) wofs[lane] = winc - wv;
            if (lane == 15) btot = winc;
        }
        __syncthreads();
        int excl = incl - v + wofs[wid] + carry;
        if (i < N_NODES) { offsets[i] = excl; cursor[i] = excl; }
        carry += btot;
        __syncthreads();   // protect wsum/wofs/btot before next chunk
    }
    if (t == 0) offsets[N_NODES] = carry;
}

// Phase C: bucket-sort col indices into CSR order. 800k int atomics w/ return.
__global__ __launch_bounds__(256) void fill_kernel(
    const int* __restrict__ row, const int* __restrict__ col,
    int* __restrict__ cursor, int* __restrict__ csr_col)
{
    int e = blockIdx.x * 256 + threadIdx.x;
    if (e < N_EDGES) {
        int r = row[e];
        int pos = atomicAdd(&cursor[r], 1);
        csr_col[pos] = col[e];
    }
}

// ---------------------------------------------------------------------------
// Phase D: fused  agg-gather + out = relu(((1+eps)x+agg)@W1+b1)@W2+b2
// One wave per node, 16 waves (1024 thr) per block so the 64 KB LDS is
// amortized: 2 blocks/CU = 2048 thr/CU = 8 waves/SIMD (was 2 with 256-thr
// blocks). launch_bounds(1024,8) caps VGPR at 64 to keep that occupancy.
// Gather is deterministic per node (contiguous csr range), unrolled x4 for
// outstanding loads. Accumulator chains split even/odd k to halve FMA
// dependency depth.
// ---------------------------------------------------------------------------
__global__ __launch_bounds__(1024, 8) void gin_fused(
    const float* __restrict__ x,
    const int*   __restrict__ offsets,
    const int*   __restrict__ csr_col,
    const float* __restrict__ W1,
    const float* __restrict__ b1,
    const float* __restrict__ W2,
    const float* __restrict__ b2,
    const float* __restrict__ eps,
    float*       __restrict__ out)
{
    __shared__ float W1s[D * H];   // 32 KB
    __shared__ float W2s[H * D];   // 32 KB

    int t = threadIdx.x;
    for (int i = t; i < D * H; i += 1024) W1s[i] = W1[i];
    for (int i = t; i < H * D; i += 1024) W2s[i] = W2[i];
    __syncthreads();

    int lane = t & 63;
    int wid  = t >> 6;
    int node = blockIdx.x * 16 + wid;
    if (node >= N_NODES) return;

    // ---- neighbor gather (wave-uniform csr reads -> scalar loads) ----
    int beg = offsets[node], end = offsets[node + 1];
    float acc = 0.0f;
    int j = beg;
    for (; j + 4 <= end; j += 4) {
        int c0 = csr_col[j], c1 = csr_col[j+1], c2 = csr_col[j+2], c3 = csr_col[j+3];
        float v0 = x[c0 * D + lane];
        float v1 = x[c1 * D + lane];
        float v2 = x[c2 * D + lane];
        float v3 = x[c3 * D + lane];
        acc += (v0 + v1) + (v2 + v3);
    }
    for (; j < end; ++j) acc += x[csr_col[j] * D + lane];

    float hv = fmaf(1.0f + eps[0], x[node * D + lane], acc);

    // ---- layer 1: hidden[j], hidden[j+64] in lanes; even/odd-k chains ----
    float a1e = b1[lane],      a1o = 0.0f;
    float a2e = b1[lane + 64], a2o = 0.0f;
    #pragma unroll
    for (int k = 0; k < D; k += 2) {
        float hk0 = __shfl(hv, k);
        float hk1 = __shfl(hv, k + 1);
        a1e = fmaf(hk0, W1s[k * H + lane],            a1e);
        a2e = fmaf(hk0, W1s[k * H + lane + 64],       a2e);
        a1o = fmaf(hk1, W1s[(k + 1) * H + lane],      a1o);
        a2o = fmaf(hk1, W1s[(k + 1) * H + lane + 64], a2o);
    }
    float h1 = fmaxf(a1e + a1o, 0.0f);   // hidden[lane]
    float h2 = fmaxf(a2e + a2o, 0.0f);   // hidden[lane+64]

    // ---- layer 2: out[lane]; two independent chains (one per hidden half) --
    float o1 = b2[lane], o2 = 0.0f;
    #pragma unroll
    for (int k = 0; k < D; ++k) {
        o1 = fmaf(__shfl(h1, k), W2s[k * D + lane],        o1);
        o2 = fmaf(__shfl(h2, k), W2s[(k + 64) * D + lane], o2);
    }

    out[node * D + lane] = o1 + o2;
}

// ---------------------------------------------------------------------------
extern "C" void kernel_launch(void* const* d_in, const int* in_sizes, int n_in,
                              void* d_out, int out_size, void* d_ws, size_t ws_size,
                              hipStream_t stream) {
    const float* x   = (const float*)d_in[0];
    const int*   ei  = (const int*)  d_in[1];   // [2, 800000] row-major
    const float* W1  = (const float*)d_in[2];
    const float* b1  = (const float*)d_in[3];
    const float* W2  = (const float*)d_in[4];
    const float* b2  = (const float*)d_in[5];
    const float* eps = (const float*)d_in[6];
    float* out = (float*)d_out;

    int* counts  = (int*)d_ws;
    int* offsets = counts + N_NODES;
    int* cursor  = offsets + (N_NODES + 1);
    int* csr_col = cursor + N_NODES;

    const int* row = ei;
    const int* col = ei + N_EDGES;

    // ws is re-poisoned to 0xAA before every timed call — zero counts each time.
    hipMemsetAsync(counts, 0, (size_t)N_NODES * sizeof(int), stream);

    hist_kernel<<<(N_EDGES + 255) / 256, 256, 0, stream>>>(row, counts);
    scan_kernel<<<1, 1024, 0, stream>>>(counts, offsets, cursor);
    fill_kernel<<<(N_EDGES + 255) / 256, 256, 0, stream>>>(row, col, cursor, csr_col);

    // 16 nodes per block (one wave per node), 3125 blocks exactly covers 50000
    gin_fused<<<(N_NODES + 15) / 16, 1024, 0, stream>>>(
        x, offsets, csr_col, W1, b1, W2, b2, eps, out);
}

// Round 3
// 216.353 us; speedup vs baseline: 4.2823x; 1.7434x over previous
//
#include <hip/hip_runtime.h>

#define N_NODES 50000
#define N_EDGES 800000
#define D 64
#define H 128
#define NBLK 196   // ceil(N_NODES / 256)

typedef __attribute__((ext_vector_type(8))) short  short8;   // 8 bf16 (A/B frag)
typedef __attribute__((ext_vector_type(4))) float  floatx4;  // C/D frag
typedef __attribute__((ext_vector_type(4))) unsigned short ushort4v;

__device__ inline unsigned short f2bf(float f) {   // round-to-nearest-even
    unsigned u = __builtin_bit_cast(unsigned, f);
    u += 0x7FFFu + ((u >> 16) & 1u);
    return (unsigned short)(u >> 16);
}
__device__ inline float bf2f(unsigned short b) {
    unsigned u = (unsigned)b << 16;
    return __builtin_bit_cast(float, u);
}

// ---------------------------------------------------------------------------
// x (fp32) -> xb (bf16), 4 elems/thread. 3.2M elems.
// ---------------------------------------------------------------------------
__global__ __launch_bounds__(256) void convert_x(
    const float* __restrict__ x, unsigned short* __restrict__ xb)
{
    int i = blockIdx.x * 256 + threadIdx.x;   // i < 800000 quads
    float4 v = ((const float4*)x)[i];
    ushort4v o;
    o.x = f2bf(v.x); o.y = f2bf(v.y); o.z = f2bf(v.z); o.w = f2bf(v.w);
    ((ushort4v*)xb)[i] = o;
}

// ---------------------------------------------------------------------------
// Histogram of destination nodes (800k int atomics).
// ---------------------------------------------------------------------------
__global__ __launch_bounds__(256) void hist_kernel(
    const int* __restrict__ row, int* __restrict__ counts)
{
    int e = blockIdx.x * 256 + threadIdx.x;
    if (e < N_EDGES) atomicAdd(&counts[row[e]], 1);
}

// ---------------------------------------------------------------------------
// Multi-block exclusive scan: (a) per-block sums, (b) scan of 196 block sums,
// (c) per-block rescan + offset. Replaces round-2's single-CU scan (~100us).
// ---------------------------------------------------------------------------
__global__ __launch_bounds__(256) void scan_a(
    const int* __restrict__ counts, int* __restrict__ bsum)
{
    int i = blockIdx.x * 256 + threadIdx.x;
    int v = (i < N_NODES) ? counts[i] : 0;
    #pragma unroll
    for (int d = 32; d; d >>= 1) v += __shfl_down(v, d);
    __shared__ int ws[4];
    int lane = threadIdx.x & 63, wid = threadIdx.x >> 6;
    if (lane == 0) ws[wid] = v;
    __syncthreads();
    if (threadIdx.x == 0) bsum[blockIdx.x] = ws[0] + ws[1] + ws[2] + ws[3];
}

__global__ __launch_bounds__(256) void scan_b(
    const int* __restrict__ bsum, int* __restrict__ bofs,
    int* __restrict__ offsets)
{
    int t = threadIdx.x, lane = t & 63, wid = t >> 6;
    int v = (t < NBLK) ? bsum[t] : 0;
    int incl = v;
    #pragma unroll
    for (int d = 1; d < 64; d <<= 1) {
        int y = __shfl_up(incl, d);
        if (lane >= d) incl += y;
    }
    __shared__ int wsum[4];
    if (lane == 63) wsum[wid] = incl;
    __syncthreads();
    int w0 = wsum[0], w1 = wsum[1], w2 = wsum[2];
    int wo = (wid == 0) ? 0 : (wid == 1) ? w0 : (wid == 2) ? w0 + w1 : w0 + w1 + w2;
    int excl = incl - v + wo;
    if (t < NBLK) bofs[t] = excl;
    if (t == NBLK - 1) offsets[N_NODES] = excl + v;   // grand total = 800000
}

__global__ __launch_bounds__(256) void scan_c(
    const int* __restrict__ counts, const int* __restrict__ bofs,
    int* __restrict__ offsets, int* __restrict__ cursor)
{
    int t = threadIdx.x, lane = t & 63, wid = t >> 6;
    int i = blockIdx.x * 256 + t;
    int v = (i < N_NODES) ? counts[i] : 0;
    int incl = v;
    #pragma unroll
    for (int d = 1; d < 64; d <<= 1) {
        int y = __shfl_up(incl, d);
        if (lane >= d) incl += y;
    }
    __shared__ int wsum[4];
    if (lane == 63) wsum[wid] = incl;
    __syncthreads();
    int w0 = wsum[0], w1 = wsum[1], w2 = wsum[2];
    int wo = (wid == 0) ? 0 : (wid == 1) ? w0 : (wid == 2) ? w0 + w1 : w0 + w1 + w2;
    int excl = incl - v + wo + bofs[blockIdx.x];
    if (i < N_NODES) { offsets[i] = excl; cursor[i] = excl; }
}

// ---------------------------------------------------------------------------
// Bucket-fill CSR columns (800k int atomics with return).
// ---------------------------------------------------------------------------
__global__ __launch_bounds__(256) void fill_kernel(
    const int* __restrict__ row, const int* __restrict__ col,
    int* __restrict__ cursor, int* __restrict__ csr_col)
{
    int e = blockIdx.x * 256 + threadIdx.x;
    if (e < N_EDGES) {
        int r = row[e];
        int pos = atomicAdd(&cursor[r], 1);
        csr_col[pos] = col[e];
    }
}

// ---------------------------------------------------------------------------
// Gather: h[node] = (1+eps)*x[node] + sum_{c in nbrs} xb[c]   -> hb (bf16)
// One wave per node; lane = feature. bf16 reads halve cache traffic.
// ---------------------------------------------------------------------------
__global__ __launch_bounds__(256) void gather_kernel(
    const float* __restrict__ x, const unsigned short* __restrict__ xb,
    const int* __restrict__ offsets, const int* __restrict__ csr_col,
    const float* __restrict__ eps, unsigned short* __restrict__ hb)
{
    int wid = threadIdx.x >> 6, lane = threadIdx.x & 63;
    int node = blockIdx.x * 4 + wid;
    if (node >= N_NODES) return;
    int beg = offsets[node], end = offsets[node + 1];
    float a0 = 0.f, a1 = 0.f, a2 = 0.f, a3 = 0.f;
    int j = beg;
    for (; j + 4 <= end; j += 4) {
        int c0 = csr_col[j], c1 = csr_col[j+1], c2 = csr_col[j+2], c3 = csr_col[j+3];
        a0 += bf2f(xb[c0 * D + lane]);
        a1 += bf2f(xb[c1 * D + lane]);
        a2 += bf2f(xb[c2 * D + lane]);
        a3 += bf2f(xb[c3 * D + lane]);
    }
    for (; j < end; ++j) a0 += bf2f(xb[csr_col[j] * D + lane]);
    float h = fmaf(1.0f + eps[0], x[node * D + lane], (a0 + a1) + (a2 + a3));
    hb[node * D + lane] = f2bf(h);
}

// ---------------------------------------------------------------------------
// MLP via bf16 MFMA 16x16x32.  Block = 4 waves, each wave owns 16 nodes.
// Layouts (guide §3, m89-verified):
//   A: lane l holds A[m = l&15][k = (l>>4)*8 + j], j=0..7   (16B contiguous)
//   B: lane l holds B[k = (l>>4)*8 + j][n = l&15]
//   D: lane l reg r -> D[row = (l>>4)*4 + r][col = l&15]
// Weights pre-transposed into LDS so B-frags are 16B ds_read_b128.
// Hidden round-trips through LDS (D-layout -> A-layout), like attention P.
// No early returns (tail waves compute garbage, stores guarded) so the two
// __syncthreads are safe.
// ---------------------------------------------------------------------------
__global__ __launch_bounds__(256) void mlp_kernel(
    const unsigned short* __restrict__ hb,
    const float* __restrict__ W1, const float* __restrict__ b1,
    const float* __restrict__ W2, const float* __restrict__ b2,
    float* __restrict__ out)
{
    __shared__ unsigned short W1T[H][72];       // [n][k], pad 64->72  (18.0 KB)
    __shared__ unsigned short W2T[D][136];      // [n2][k], pad 128->136 (17.4 KB)
    __shared__ unsigned short HID[4][16][136];  // per-wave hidden tile  (17.4 KB)

    int t = threadIdx.x;
    for (int i = t; i < D * H; i += 256) {      // W1: [k=i>>7][n=i&127]
        W1T[i & 127][i >> 7] = f2bf(W1[i]);
    }
    for (int i = t; i < H * D; i += 256) {      // W2: [k=i>>6][n=i&63]
        W2T[i & 63][i >> 6] = f2bf(W2[i]);
    }
    __syncthreads();

    int lane = t & 63, wid = t >> 6;
    int m = lane & 15, q = lane >> 4;           // q = quad 0..3
    int tile = blockIdx.x * 64 + wid * 16;      // first node of this wave

    // ---- A-frags for layer 1 (from hb, global; 16B loads) ----
    const unsigned short* arow = hb + (tile + m) * D + q * 8;
    short8 a0 = *(const short8*)(arow);         // k 0..31
    short8 a1 = *(const short8*)(arow + 32);    // k 32..63

    // ---- layer 1: hidden[16 x 128] = relu(h @ W1 + b1) ----
    #pragma unroll
    for (int nt = 0; nt < 8; ++nt) {
        float bias = b1[nt * 16 + m];
        floatx4 acc = {bias, bias, bias, bias};
        short8 w0 = *(const short8*)&W1T[nt * 16 + m][q * 8];
        short8 w1 = *(const short8*)&W1T[nt * 16 + m][32 + q * 8];
        acc = __builtin_amdgcn_mfma_f32_16x16x32_bf16(a0, w0, acc, 0, 0, 0);
        acc = __builtin_amdgcn_mfma_f32_16x16x32_bf16(a1, w1, acc, 0, 0, 0);
        #pragma unroll
        for (int r = 0; r < 4; ++r) {
            float hv = fmaxf(acc[r], 0.0f);
            HID[wid][q * 4 + r][nt * 16 + m] = f2bf(hv);   // D-layout -> [m][n]
        }
    }
    __syncthreads();   // order HID writes before reads (all waves present)

    // ---- A-frags for layer 2 (from HID; 16B ds_read_b128) ----
    short8 ha[4];
    #pragma unroll
    for (int kc = 0; kc < 4; ++kc)
        ha[kc] = *(const short8*)&HID[wid][m][kc * 32 + q * 8];

    // ---- layer 2: out[16 x 64] = hidden @ W2 + b2 ----
    #pragma unroll
    for (int nt2 = 0; nt2 < 4; ++nt2) {
        float bias = b2[nt2 * 16 + m];
        floatx4 acc = {bias, bias, bias, bias};
        #pragma unroll
        for (int kc = 0; kc < 4; ++kc) {
            short8 w = *(const short8*)&W2T[nt2 * 16 + m][kc * 32 + q * 8];
            acc = __builtin_amdgcn_mfma_f32_16x16x32_bf16(ha[kc], w, acc, 0, 0, 0);
        }
        #pragma unroll
        for (int r = 0; r < 4; ++r) {
            int node = tile + q * 4 + r;
            if (node < N_NODES) out[node * D + nt2 * 16 + m] = acc[r];
        }
    }
}

// ---------------------------------------------------------------------------
extern "C" void kernel_launch(void* const* d_in, const int* in_sizes, int n_in,
                              void* d_out, int out_size, void* d_ws, size_t ws_size,
                              hipStream_t stream) {
    const float* x   = (const float*)d_in[0];
    const int*   ei  = (const int*)  d_in[1];   // [2, 800000] int32 (x64 disabled)
    const float* W1  = (const float*)d_in[2];
    const float* b1  = (const float*)d_in[3];
    const float* W2  = (const float*)d_in[4];
    const float* b2  = (const float*)d_in[5];
    const float* eps = (const float*)d_in[6];
    float* out = (float*)d_out;

    // ws layout: hb first for 16B alignment of bf16x8 loads. Total ~10.2 MB.
    unsigned short* hb  = (unsigned short*)d_ws;          // 50000*64 bf16, 6.4 MB
    int* csr_col = (int*)(hb + (size_t)N_NODES * D);      // 800000
    int* counts  = csr_col + N_EDGES;                     // 50000
    int* offsets = counts + N_NODES;                      // 50001
    int* cursor  = offsets + N_NODES + 1;                 // 50000
    int* bsum    = cursor + N_NODES;                      // 196
    int* bofs    = bsum + NBLK;                           // 196

    // xb (bf16 copy of x) lives in d_out: consumed by gather before mlp writes.
    unsigned short* xb = (unsigned short*)d_out;

    const int* row = ei;
    const int* col = ei + N_EDGES;

    hipMemsetAsync(counts, 0, (size_t)N_NODES * sizeof(int), stream);

    convert_x<<<(N_NODES * D / 4 + 255) / 256, 256, 0, stream>>>(x, xb);
    hist_kernel<<<(N_EDGES + 255) / 256, 256, 0, stream>>>(row, counts);
    scan_a<<<NBLK, 256, 0, stream>>>(counts, bsum);
    scan_b<<<1, 256, 0, stream>>>(bsum, bofs, offsets);
    scan_c<<<NBLK, 256, 0, stream>>>(counts, bofs, offsets, cursor);
    fill_kernel<<<(N_EDGES + 255) / 256, 256, 0, stream>>>(row, col, cursor, csr_col);
    gather_kernel<<<(N_NODES + 3) / 4, 256, 0, stream>>>(x, xb, offsets, csr_col, eps, hb);
    mlp_kernel<<<(N_NODES + 63) / 64, 256, 0, stream>>>(hb, W1, b1, W2, b2, out);
}